// Round 1
// baseline (3509.415 us; speedup 1.0000x reference)
//
#include <hip/hip_runtime.h>

#define N_NODES 50000

// C[M,N] = act(A[M,K]) @ W[K,N] + b    (act = relu if RELU_A)
template<int K, int N, bool RELU_A>
__global__ __launch_bounds__(256) void gemm_kernel(const float* __restrict__ A,
                                                   const float* __restrict__ W,
                                                   const float* __restrict__ b,
                                                   float* __restrict__ C, int M)
{
    __shared__ __align__(16) float As[16][K];
    const int row0 = blockIdx.x * 16;
    const int tid  = threadIdx.x;

    // Stage 16 rows of A into LDS with float4 loads (+fused ReLU).
    constexpr int NV = 16 * K / 4;          // number of float4 elements
    for (int i = tid; i < NV; i += 256) {
        const int r  = i / (K / 4);
        const int kk = (i % (K / 4)) * 4;
        const int gr = row0 + r;
        float4 v = make_float4(0.f, 0.f, 0.f, 0.f);
        if (gr < M) v = *reinterpret_cast<const float4*>(&A[(size_t)gr * K + kk]);
        if (RELU_A) {
            v.x = fmaxf(v.x, 0.f); v.y = fmaxf(v.y, 0.f);
            v.z = fmaxf(v.z, 0.f); v.w = fmaxf(v.w, 0.f);
        }
        *reinterpret_cast<float4*>(&As[r][kk]) = v;
    }
    __syncthreads();

    constexpr int RG  = 256 / N;    // row-groups per block (2 for N=128, 4 for N=64)
    constexpr int RPT = 16 / RG;    // rows per thread (8 or 4)
    const int col = tid & (N - 1);
    const int rg  = tid / N;

    float acc[RPT];
#pragma unroll
    for (int i = 0; i < RPT; ++i) acc[i] = 0.f;

    for (int k = 0; k < K; ++k) {
        const float wv = W[k * N + col];    // L2-resident, broadcast across row-groups
#pragma unroll
        for (int i = 0; i < RPT; ++i)
            acc[i] = fmaf(As[rg * RPT + i][k], wv, acc[i]);
    }

    const float bias = b[col];
#pragma unroll
    for (int i = 0; i < RPT; ++i) {
        const int gr = row0 + rg * RPT + i;
        if (gr < M) C[(size_t)gr * N + col] = acc[i] + bias;
    }
}

// out[dst[e]] += h[src[e]] * w[e], D dims per edge, D/4 threads per edge.
template<int D>
__global__ __launch_bounds__(256) void scatter_kernel(const float* __restrict__ h,
                                                      const int* __restrict__ src,
                                                      const int* __restrict__ dst,
                                                      const float* __restrict__ w,
                                                      float* __restrict__ out, int E)
{
    constexpr int TPE = D / 4;              // threads per edge
    const long long gid   = (long long)blockIdx.x * blockDim.x + threadIdx.x;
    const long long total = (long long)E * TPE;
    if (gid >= total) return;
    const int e = (int)(gid / TPE);
    const int d = (int)(gid % TPE) * 4;

    const int   s  = src[e];
    const int   t  = dst[e];
    const float ww = w[e];

    const float4 v = *reinterpret_cast<const float4*>(&h[(size_t)s * D + d]);
    float* o = &out[(size_t)t * D + d];
    atomicAdd(o + 0, v.x * ww);
    atomicAdd(o + 1, v.y * ww);
    atomicAdd(o + 2, v.z * ww);
    atomicAdd(o + 3, v.w * ww);
}

extern "C" void kernel_launch(void* const* d_in, const int* in_sizes, int n_in,
                              void* d_out, int out_size, void* d_ws, size_t ws_size,
                              hipStream_t stream)
{
    const float* x   = (const float*)d_in[0];
    const int*   src = (const int*)  d_in[1];
    const int*   dst = (const int*)  d_in[2];
    const float* w   = (const float*)d_in[3];
    const float* W1  = (const float*)d_in[4];
    const float* b1  = (const float*)d_in[5];
    const float* W2  = (const float*)d_in[6];
    const float* b2  = (const float*)d_in[7];
    const float* W3  = (const float*)d_in[8];
    const float* b3  = (const float*)d_in[9];

    const int E = in_sizes[1];
    const int M = N_NODES;

    float* bufA = (float*)d_ws;                 // t1 / t2 / t3
    float* bufB = bufA + (size_t)M * 128;       // a1(relu) / a2(relu)
    float* out  = (float*)d_out;

    const size_t SZ128 = (size_t)M * 128 * sizeof(float);
    const size_t SZ64  = (size_t)M * 64  * sizeof(float);

    const int gemm_blocks = (M + 15) / 16;      // 3125

    // Layer 1: t1 = x @ W1 + b1 ; a1 = scatter(t1)
    gemm_kernel<256, 128, false><<<gemm_blocks, 256, 0, stream>>>(x, W1, b1, bufA, M);
    hipMemsetAsync(bufB, 0, SZ128, stream);
    {
        const long long total = (long long)E * 32;
        const int blocks = (int)((total + 255) / 256);
        scatter_kernel<128><<<blocks, 256, 0, stream>>>(bufA, src, dst, w, bufB, E);
    }

    // Layer 2: t2 = relu(a1) @ W2 + b2 ; a2 = scatter(t2)
    gemm_kernel<128, 128, true><<<gemm_blocks, 256, 0, stream>>>(bufB, W2, b2, bufA, M);
    hipMemsetAsync(bufB, 0, SZ128, stream);
    {
        const long long total = (long long)E * 32;
        const int blocks = (int)((total + 255) / 256);
        scatter_kernel<128><<<blocks, 256, 0, stream>>>(bufA, src, dst, w, bufB, E);
    }

    // Layer 3: t3 = relu(a2) @ W3 + b3 ; out = scatter(t3)
    gemm_kernel<128, 64, true><<<gemm_blocks, 256, 0, stream>>>(bufB, W3, b3, bufA, M);
    hipMemsetAsync(out, 0, SZ64, stream);
    {
        const long long total = (long long)E * 16;
        const int blocks = (int)((total + 255) / 256);
        scatter_kernel<64><<<blocks, 256, 0, stream>>>(bufA, src, dst, w, out, E);
    }
}

// Round 2
// 575.128 us; speedup vs baseline: 6.1020x; 6.1020x over previous
//
#include <hip/hip_runtime.h>

#define N_NODES 50000

// ---------------- GEMM: C[M,N] = act(A[M,K]) @ W[K,N] + b ----------------
template<int K, int N, bool RELU_A>
__global__ __launch_bounds__(256) void gemm_kernel(const float* __restrict__ A,
                                                   const float* __restrict__ W,
                                                   const float* __restrict__ b,
                                                   float* __restrict__ C, int M)
{
    __shared__ __align__(16) float As[16][K];
    const int row0 = blockIdx.x * 16;
    const int tid  = threadIdx.x;

    constexpr int NV = 16 * K / 4;
    for (int i = tid; i < NV; i += 256) {
        const int r  = i / (K / 4);
        const int kk = (i % (K / 4)) * 4;
        const int gr = row0 + r;
        float4 v = make_float4(0.f, 0.f, 0.f, 0.f);
        if (gr < M) v = *reinterpret_cast<const float4*>(&A[(size_t)gr * K + kk]);
        if (RELU_A) {
            v.x = fmaxf(v.x, 0.f); v.y = fmaxf(v.y, 0.f);
            v.z = fmaxf(v.z, 0.f); v.w = fmaxf(v.w, 0.f);
        }
        *reinterpret_cast<float4*>(&As[r][kk]) = v;
    }
    __syncthreads();

    constexpr int RG  = 256 / N;
    constexpr int RPT = 16 / RG;
    const int col = tid & (N - 1);
    const int rg  = tid / N;

    float acc[RPT];
#pragma unroll
    for (int i = 0; i < RPT; ++i) acc[i] = 0.f;

    for (int k = 0; k < K; ++k) {
        const float wv = W[k * N + col];
#pragma unroll
        for (int i = 0; i < RPT; ++i)
            acc[i] = fmaf(As[rg * RPT + i][k], wv, acc[i]);
    }

    const float bias = b[col];
#pragma unroll
    for (int i = 0; i < RPT; ++i) {
        const int gr = row0 + rg * RPT + i;
        if (gr < M) C[(size_t)gr * N + col] = acc[i] + bias;
    }
}

// ---------------- CSR build ----------------
__global__ __launch_bounds__(256) void hist_kernel(const int* __restrict__ dst,
                                                   int* __restrict__ deg, int E)
{
    const int i = blockIdx.x * 256 + threadIdx.x;
    if (i < E) atomicAdd(&deg[dst[i]], 1);
}

// Single-block exclusive scan over n counters. On entry deg_cursor[i] = degree.
// On exit: row_ptr[i] = exclusive prefix, row_ptr[n] = total, deg_cursor[i] = row_ptr[i].
__global__ __launch_bounds__(1024) void scan_kernel(int* __restrict__ deg_cursor,
                                                    int* __restrict__ row_ptr, int n)
{
    __shared__ int sums[1024];
    const int t = threadIdx.x;
    const int C = (n + 1023) / 1024;
    const int beg = t * C;
    const int end = min(beg + C, n);

    int s = 0;
    for (int i = beg; i < end; ++i) s += deg_cursor[i];
    sums[t] = s;
    __syncthreads();

    for (int off = 1; off < 1024; off <<= 1) {
        const int tmp = (t >= off) ? sums[t - off] : 0;
        __syncthreads();
        sums[t] += tmp;
        __syncthreads();
    }

    int run = (t == 0) ? 0 : sums[t - 1];
    for (int i = beg; i < end; ++i) {
        const int d = deg_cursor[i];
        row_ptr[i]    = run;
        deg_cursor[i] = run;    // cursor init for fill
        run += d;
    }
    if (t == 1023) row_ptr[n] = sums[1023];
}

__global__ __launch_bounds__(256) void fill_kernel(const int* __restrict__ src,
                                                   const int* __restrict__ dst,
                                                   const float* __restrict__ w,
                                                   int* __restrict__ cursor,
                                                   int* __restrict__ csr_src,
                                                   float* __restrict__ csr_w, int E)
{
    const int i = blockIdx.x * 256 + threadIdx.x;
    if (i < E) {
        const int t   = dst[i];
        const int pos = atomicAdd(&cursor[t], 1);
        csr_src[pos] = src[i];
        csr_w[pos]   = w[i];
    }
}

// ---------------- pull segment-sum: out[n] = sum_e w_e * h[src_e] ----------------
// One wave (64 lanes) per node. D=128: float2 per lane; D=64: float per lane.
template<int D>
__global__ __launch_bounds__(256) void pull_kernel(const float* __restrict__ h,
                                                   const int* __restrict__ row_ptr,
                                                   const int* __restrict__ csr_src,
                                                   const float* __restrict__ csr_w,
                                                   float* __restrict__ out, int n_nodes)
{
    const int wave = threadIdx.x >> 6;
    const int lane = threadIdx.x & 63;
    const int node = blockIdx.x * 4 + wave;
    if (node >= n_nodes) return;

    const int beg = row_ptr[node];
    const int end = row_ptr[node + 1];

    if (D == 128) {
        float2 acc = make_float2(0.f, 0.f);
        for (int i = beg; i < end; ++i) {
            const int   s  = csr_src[i];
            const float ww = csr_w[i];
            const float2 v = *reinterpret_cast<const float2*>(&h[(size_t)s * 128 + 2 * lane]);
            acc.x = fmaf(v.x, ww, acc.x);
            acc.y = fmaf(v.y, ww, acc.y);
        }
        *reinterpret_cast<float2*>(&out[(size_t)node * 128 + 2 * lane]) = acc;
    } else {
        float acc = 0.f;
        for (int i = beg; i < end; ++i) {
            const int   s  = csr_src[i];
            const float ww = csr_w[i];
            acc = fmaf(h[(size_t)s * 64 + lane], ww, acc);
        }
        out[(size_t)node * 64 + lane] = acc;
    }
}

extern "C" void kernel_launch(void* const* d_in, const int* in_sizes, int n_in,
                              void* d_out, int out_size, void* d_ws, size_t ws_size,
                              hipStream_t stream)
{
    const float* x   = (const float*)d_in[0];
    const int*   src = (const int*)  d_in[1];
    const int*   dst = (const int*)  d_in[2];
    const float* w   = (const float*)d_in[3];
    const float* W1  = (const float*)d_in[4];
    const float* b1  = (const float*)d_in[5];
    const float* W2  = (const float*)d_in[6];
    const float* b2  = (const float*)d_in[7];
    const float* W3  = (const float*)d_in[8];
    const float* b3  = (const float*)d_in[9];

    const int E = in_sizes[1];
    const int M = N_NODES;

    // workspace layout
    float* bufA    = (float*)d_ws;                       // 50000*128 floats
    float* bufB    = bufA + (size_t)M * 128;             // 50000*128 floats
    int*   row_ptr = (int*)(bufB + (size_t)M * 128);     // 50001 (padded to 50048)
    int*   cursor  = row_ptr + 50048;                    // 50000 (padded to 50048)
    int*   csr_src = cursor + 50048;                     // E
    float* csr_w   = (float*)(csr_src + E);              // E

    const int eb = (E + 255) / 256;          // 3125 edge-blocks
    const int gemm_blocks = (M + 15) / 16;   // 3125
    const int pull_blocks = (M + 3) / 4;     // 12500

    // ---- CSR build (once, reused by all 3 layers) ----
    hipMemsetAsync(cursor, 0, (size_t)M * sizeof(int), stream);
    hist_kernel<<<eb, 256, 0, stream>>>(dst, cursor, E);
    scan_kernel<<<1, 1024, 0, stream>>>(cursor, row_ptr, M);
    fill_kernel<<<eb, 256, 0, stream>>>(src, dst, w, cursor, csr_src, csr_w, E);

    // ---- Layer 1 ----
    gemm_kernel<256, 128, false><<<gemm_blocks, 256, 0, stream>>>(x, W1, b1, bufA, M);
    pull_kernel<128><<<pull_blocks, 256, 0, stream>>>(bufA, row_ptr, csr_src, csr_w, bufB, M);

    // ---- Layer 2 ----
    gemm_kernel<128, 128, true><<<gemm_blocks, 256, 0, stream>>>(bufB, W2, b2, bufA, M);
    pull_kernel<128><<<pull_blocks, 256, 0, stream>>>(bufA, row_ptr, csr_src, csr_w, bufB, M);

    // ---- Layer 3 ----
    gemm_kernel<128, 64, true><<<gemm_blocks, 256, 0, stream>>>(bufB, W3, b3, bufA, M);
    pull_kernel<64><<<pull_blocks, 256, 0, stream>>>(bufA, row_ptr, csr_src, csr_w, (float*)d_out, M);
}

// Round 3
// 402.088 us; speedup vs baseline: 8.7280x; 1.4304x over previous
//
#include <hip/hip_runtime.h>

#define N_NODES 50000

// ---------------- GEMM: C[M,N] = act(A[M,K]) @ W[K,N] + b ----------------
template<int K, int N, bool RELU_A>
__global__ __launch_bounds__(256) void gemm_kernel(const float* __restrict__ A,
                                                   const float* __restrict__ W,
                                                   const float* __restrict__ b,
                                                   float* __restrict__ C, int M)
{
    __shared__ __align__(16) float As[16][K];
    const int row0 = blockIdx.x * 16;
    const int tid  = threadIdx.x;

    constexpr int NV = 16 * K / 4;
    for (int i = tid; i < NV; i += 256) {
        const int r  = i / (K / 4);
        const int kk = (i % (K / 4)) * 4;
        const int gr = row0 + r;
        float4 v = make_float4(0.f, 0.f, 0.f, 0.f);
        if (gr < M) v = *reinterpret_cast<const float4*>(&A[(size_t)gr * K + kk]);
        if (RELU_A) {
            v.x = fmaxf(v.x, 0.f); v.y = fmaxf(v.y, 0.f);
            v.z = fmaxf(v.z, 0.f); v.w = fmaxf(v.w, 0.f);
        }
        *reinterpret_cast<float4*>(&As[r][kk]) = v;
    }
    __syncthreads();

    constexpr int RG  = 256 / N;
    constexpr int RPT = 16 / RG;
    const int col = tid & (N - 1);
    const int rg  = tid / N;

    float acc[RPT];
#pragma unroll
    for (int i = 0; i < RPT; ++i) acc[i] = 0.f;

    for (int k = 0; k < K; ++k) {
        const float wv = W[k * N + col];
#pragma unroll
        for (int i = 0; i < RPT; ++i)
            acc[i] = fmaf(As[rg * RPT + i][k], wv, acc[i]);
    }

    const float bias = b[col];
#pragma unroll
    for (int i = 0; i < RPT; ++i) {
        const int gr = row0 + rg * RPT + i;
        if (gr < M) C[(size_t)gr * N + col] = acc[i] + bias;
    }
}

// ---------------- CSR build ----------------
__global__ __launch_bounds__(256) void hist_kernel(const int* __restrict__ dst,
                                                   int* __restrict__ deg, int E)
{
    const int i = blockIdx.x * 256 + threadIdx.x;
    if (i < E) atomicAdd(&deg[dst[i]], 1);
}

// Phase 1: per-block sums of deg (256 elems/block).
__global__ __launch_bounds__(256) void scan_partial(const int* __restrict__ deg,
                                                    int* __restrict__ partial, int n)
{
    __shared__ int red[4];
    const int t = threadIdx.x;
    const int i = blockIdx.x * 256 + t;
    int v = (i < n) ? deg[i] : 0;
#pragma unroll
    for (int off = 32; off > 0; off >>= 1) v += __shfl_down(v, off, 64);
    if ((t & 63) == 0) red[t >> 6] = v;
    __syncthreads();
    if (t == 0) partial[blockIdx.x] = red[0] + red[1] + red[2] + red[3];
}

// Phase 2: single-block exclusive scan of partial[0..nb), nb <= 256.
__global__ __launch_bounds__(256) void scan_offsets(int* __restrict__ partial, int nb)
{
    __shared__ int s[256];
    const int t = threadIdx.x;
    const int v = (t < nb) ? partial[t] : 0;
    s[t] = v;
    __syncthreads();
#pragma unroll
    for (int off = 1; off < 256; off <<= 1) {
        const int tmp = (t >= off) ? s[t - off] : 0;
        __syncthreads();
        s[t] += tmp;
        __syncthreads();
    }
    if (t < nb) partial[t] = s[t] - v;   // exclusive
}

// Phase 3: block-local exclusive scan + block offset -> row_ptr, cursor.
__global__ __launch_bounds__(256) void scan_final(const int* __restrict__ deg,
                                                  const int* __restrict__ partial,
                                                  int* __restrict__ row_ptr,
                                                  int* __restrict__ cursor, int n, int E)
{
    __shared__ int s[256];
    const int t = threadIdx.x;
    const int i = blockIdx.x * 256 + t;
    const int v = (i < n) ? deg[i] : 0;
    s[t] = v;
    __syncthreads();
#pragma unroll
    for (int off = 1; off < 256; off <<= 1) {
        const int tmp = (t >= off) ? s[t - off] : 0;
        __syncthreads();
        s[t] += tmp;
        __syncthreads();
    }
    const int excl = s[t] - v + partial[blockIdx.x];
    if (i < n) { row_ptr[i] = excl; cursor[i] = excl; }
    if (i == 0) row_ptr[n] = E;
}

// Fill packed (src, w) CSR entries (8 B per edge).
__global__ __launch_bounds__(256) void fill_kernel(const int* __restrict__ src,
                                                   const int* __restrict__ dst,
                                                   const float* __restrict__ w,
                                                   int* __restrict__ cursor,
                                                   int2* __restrict__ csr_ew, int E)
{
    const int i = blockIdx.x * 256 + threadIdx.x;
    if (i < E) {
        const int t   = dst[i];
        const int pos = atomicAdd(&cursor[t], 1);
        int2 ew;
        ew.x = src[i];
        ew.y = __float_as_int(w[i]);
        csr_ew[pos] = ew;
    }
}

// ---------------- pull segment-sum: out[n] = sum_e w_e * h[src_e] ----------------
// One wave per node; D=128 -> float2/lane, D=64 -> float/lane. 2-edge ILP unroll.
template<int D>
__global__ __launch_bounds__(256) void pull_kernel(const float* __restrict__ h,
                                                   const int* __restrict__ row_ptr,
                                                   const int2* __restrict__ csr_ew,
                                                   float* __restrict__ out, int n_nodes)
{
    const int wave = threadIdx.x >> 6;
    const int lane = threadIdx.x & 63;
    const int node = blockIdx.x * 4 + wave;
    if (node >= n_nodes) return;

    const int beg = row_ptr[node];
    const int end = row_ptr[node + 1];

    if (D == 128) {
        float2 a0 = make_float2(0.f, 0.f);
        float2 a1 = make_float2(0.f, 0.f);
        int i = beg;
        for (; i + 1 < end; i += 2) {
            const int2 e0 = csr_ew[i];
            const int2 e1 = csr_ew[i + 1];
            const float w0 = __int_as_float(e0.y);
            const float w1 = __int_as_float(e1.y);
            const float2 v0 = *reinterpret_cast<const float2*>(&h[(size_t)e0.x * 128 + 2 * lane]);
            const float2 v1 = *reinterpret_cast<const float2*>(&h[(size_t)e1.x * 128 + 2 * lane]);
            a0.x = fmaf(v0.x, w0, a0.x); a0.y = fmaf(v0.y, w0, a0.y);
            a1.x = fmaf(v1.x, w1, a1.x); a1.y = fmaf(v1.y, w1, a1.y);
        }
        if (i < end) {
            const int2 e0 = csr_ew[i];
            const float w0 = __int_as_float(e0.y);
            const float2 v0 = *reinterpret_cast<const float2*>(&h[(size_t)e0.x * 128 + 2 * lane]);
            a0.x = fmaf(v0.x, w0, a0.x); a0.y = fmaf(v0.y, w0, a0.y);
        }
        a0.x += a1.x; a0.y += a1.y;
        *reinterpret_cast<float2*>(&out[(size_t)node * 128 + 2 * lane]) = a0;
    } else {
        float a0 = 0.f, a1 = 0.f;
        int i = beg;
        for (; i + 1 < end; i += 2) {
            const int2 e0 = csr_ew[i];
            const int2 e1 = csr_ew[i + 1];
            a0 = fmaf(h[(size_t)e0.x * 64 + lane], __int_as_float(e0.y), a0);
            a1 = fmaf(h[(size_t)e1.x * 64 + lane], __int_as_float(e1.y), a1);
        }
        if (i < end) {
            const int2 e0 = csr_ew[i];
            a0 = fmaf(h[(size_t)e0.x * 64 + lane], __int_as_float(e0.y), a0);
        }
        out[(size_t)node * 64 + lane] = a0 + a1;
    }
}

extern "C" void kernel_launch(void* const* d_in, const int* in_sizes, int n_in,
                              void* d_out, int out_size, void* d_ws, size_t ws_size,
                              hipStream_t stream)
{
    const float* x   = (const float*)d_in[0];
    const int*   src = (const int*)  d_in[1];
    const int*   dst = (const int*)  d_in[2];
    const float* w   = (const float*)d_in[3];
    const float* W1  = (const float*)d_in[4];
    const float* b1  = (const float*)d_in[5];
    const float* W2  = (const float*)d_in[6];
    const float* b2  = (const float*)d_in[7];
    const float* W3  = (const float*)d_in[8];
    const float* b3  = (const float*)d_in[9];

    const int E = in_sizes[1];
    const int M = N_NODES;

    // workspace layout (8B-aligned segments)
    float* bufA    = (float*)d_ws;                        // M*128 f32
    float* bufB    = bufA + (size_t)M * 128;              // M*128 f32
    int2*  csr_ew  = (int2*)(bufB + (size_t)M * 128);     // E pairs (8 B)
    int*   row_ptr = (int*)(csr_ew + E);                  // 50048
    int*   cursor  = row_ptr + 50048;                     // 50048
    int*   deg     = cursor + 50048;                      // 50048
    int*   partial = deg + 50048;                         // 256

    const int eb = (E + 255) / 256;           // edge blocks
    const int nb = (M + 255) / 256;           // node blocks (196)
    const int gemm_blocks = (M + 15) / 16;
    const int pull_blocks = (M + 3) / 4;

    // ---- CSR build (once per call, reused by all 3 layers) ----
    hipMemsetAsync(deg, 0, (size_t)M * sizeof(int), stream);
    hist_kernel<<<eb, 256, 0, stream>>>(dst, deg, E);
    scan_partial<<<nb, 256, 0, stream>>>(deg, partial, M);
    scan_offsets<<<1, 256, 0, stream>>>(partial, nb);
    scan_final<<<nb, 256, 0, stream>>>(deg, partial, row_ptr, cursor, M, E);
    fill_kernel<<<eb, 256, 0, stream>>>(src, dst, w, cursor, csr_ew, E);

    // ---- Layer 1 ----
    gemm_kernel<256, 128, false><<<gemm_blocks, 256, 0, stream>>>(x, W1, b1, bufA, M);
    pull_kernel<128><<<pull_blocks, 256, 0, stream>>>(bufA, row_ptr, csr_ew, bufB, M);

    // ---- Layer 2 ----
    gemm_kernel<128, 128, true><<<gemm_blocks, 256, 0, stream>>>(bufB, W2, b2, bufA, M);
    pull_kernel<128><<<pull_blocks, 256, 0, stream>>>(bufA, row_ptr, csr_ew, bufB, M);

    // ---- Layer 3 ----
    gemm_kernel<128, 64, true><<<gemm_blocks, 256, 0, stream>>>(bufB, W3, b3, bufA, M);
    pull_kernel<64><<<pull_blocks, 256, 0, stream>>>(bufA, row_ptr, csr_ew, (float*)d_out, M);
}

// Round 4
// 375.347 us; speedup vs baseline: 9.3498x; 1.0712x over previous
//
#include <hip/hip_runtime.h>

#define N_NODES 50000

// ---------------- GEMM: C[M,N] = act(A[M,K]) @ W[K,N] + b ----------------
// Register-tiled: BM=64, BK=32, BN=N. 256 threads; each computes RPT rows x 4 cols.
template<int K, int N, bool RELU_A>
__global__ __launch_bounds__(256) void gemm_kernel(const float* __restrict__ A,
                                                   const float* __restrict__ W,
                                                   const float* __restrict__ b,
                                                   float* __restrict__ C, int M)
{
    constexpr int BM = 64;
    constexpr int BK = 32;
    constexpr int TCOLS = N / 4;          // 32 (N=128) or 16 (N=64)
    constexpr int TROWS = 256 / TCOLS;    // 8 or 16
    constexpr int RPT   = BM / TROWS;     // 8 or 4

    __shared__ __align__(16) float As[BM][BK + 4];   // stride 36 floats = 144B (16B-aligned rows)
    __shared__ __align__(16) float Ws[BK][N];

    const int tid  = threadIdx.x;
    const int row0 = blockIdx.x * BM;
    const int tx   = tid % TCOLS;
    const int ty   = tid / TCOLS;

    float4 acc[RPT];
#pragma unroll
    for (int i = 0; i < RPT; ++i) acc[i] = make_float4(0.f, 0.f, 0.f, 0.f);

    for (int k0 = 0; k0 < K; k0 += BK) {
        // --- stage A tile (64 x 32), fused ReLU ---
#pragma unroll
        for (int i = tid; i < BM * (BK / 4); i += 256) {
            const int r  = i >> 3;            // BK/4 = 8
            const int kq = (i & 7) * 4;
            const int gr = row0 + r;
            float4 v = make_float4(0.f, 0.f, 0.f, 0.f);
            if (gr < M) v = *reinterpret_cast<const float4*>(&A[(size_t)gr * K + k0 + kq]);
            if (RELU_A) {
                v.x = fmaxf(v.x, 0.f); v.y = fmaxf(v.y, 0.f);
                v.z = fmaxf(v.z, 0.f); v.w = fmaxf(v.w, 0.f);
            }
            *reinterpret_cast<float4*>(&As[r][kq]) = v;
        }
        // --- stage W tile (32 x N) ---
#pragma unroll
        for (int i = tid; i < BK * (N / 4); i += 256) {
            const int r  = i / (N / 4);
            const int c4 = (i % (N / 4)) * 4;
            const float4 v = *reinterpret_cast<const float4*>(&W[(size_t)(k0 + r) * N + c4]);
            *reinterpret_cast<float4*>(&Ws[r][c4]) = v;
        }
        __syncthreads();

        // --- compute: chunks of 4 k ---
#pragma unroll
        for (int kc = 0; kc < BK; kc += 4) {
            float4 wv[4];
#pragma unroll
            for (int kk = 0; kk < 4; ++kk)
                wv[kk] = *reinterpret_cast<const float4*>(&Ws[kc + kk][tx * 4]);

            float4 av[RPT];
#pragma unroll
            for (int i = 0; i < RPT; ++i)
                av[i] = *reinterpret_cast<const float4*>(&As[ty * RPT + i][kc]);

#pragma unroll
            for (int i = 0; i < RPT; ++i) {
                const float* ap = reinterpret_cast<const float*>(&av[i]);
#pragma unroll
                for (int kk = 0; kk < 4; ++kk) {
                    acc[i].x = fmaf(ap[kk], wv[kk].x, acc[i].x);
                    acc[i].y = fmaf(ap[kk], wv[kk].y, acc[i].y);
                    acc[i].z = fmaf(ap[kk], wv[kk].z, acc[i].z);
                    acc[i].w = fmaf(ap[kk], wv[kk].w, acc[i].w);
                }
            }
        }
        __syncthreads();
    }

    const float4 bias = *reinterpret_cast<const float4*>(&b[tx * 4]);
#pragma unroll
    for (int i = 0; i < RPT; ++i) {
        const int gr = row0 + ty * RPT + i;
        if (gr < M) {
            float4 v = acc[i];
            v.x += bias.x; v.y += bias.y; v.z += bias.z; v.w += bias.w;
            *reinterpret_cast<float4*>(&C[(size_t)gr * N + tx * 4]) = v;
        }
    }
}

// ---------------- CSR build ----------------
__global__ __launch_bounds__(256) void hist_kernel(const int* __restrict__ dst,
                                                   int* __restrict__ deg, int E)
{
    const int i = blockIdx.x * 256 + threadIdx.x;
    if (i < E) atomicAdd(&deg[dst[i]], 1);
}

__global__ __launch_bounds__(256) void scan_partial(const int* __restrict__ deg,
                                                    int* __restrict__ partial, int n)
{
    __shared__ int red[4];
    const int t = threadIdx.x;
    const int i = blockIdx.x * 256 + t;
    int v = (i < n) ? deg[i] : 0;
#pragma unroll
    for (int off = 32; off > 0; off >>= 1) v += __shfl_down(v, off, 64);
    if ((t & 63) == 0) red[t >> 6] = v;
    __syncthreads();
    if (t == 0) partial[blockIdx.x] = red[0] + red[1] + red[2] + red[3];
}

__global__ __launch_bounds__(256) void scan_offsets(int* __restrict__ partial, int nb)
{
    __shared__ int s[256];
    const int t = threadIdx.x;
    const int v = (t < nb) ? partial[t] : 0;
    s[t] = v;
    __syncthreads();
#pragma unroll
    for (int off = 1; off < 256; off <<= 1) {
        const int tmp = (t >= off) ? s[t - off] : 0;
        __syncthreads();
        s[t] += tmp;
        __syncthreads();
    }
    if (t < nb) partial[t] = s[t] - v;   // exclusive
}

__global__ __launch_bounds__(256) void scan_final(const int* __restrict__ deg,
                                                  const int* __restrict__ partial,
                                                  int* __restrict__ row_ptr,
                                                  int* __restrict__ cursor, int n, int E)
{
    __shared__ int s[256];
    const int t = threadIdx.x;
    const int i = blockIdx.x * 256 + t;
    const int v = (i < n) ? deg[i] : 0;
    s[t] = v;
    __syncthreads();
#pragma unroll
    for (int off = 1; off < 256; off <<= 1) {
        const int tmp = (t >= off) ? s[t - off] : 0;
        __syncthreads();
        s[t] += tmp;
        __syncthreads();
    }
    const int excl = s[t] - v + partial[blockIdx.x];
    if (i < n) { row_ptr[i] = excl; cursor[i] = excl; }
    if (i == 0) row_ptr[n] = E;
}

__global__ __launch_bounds__(256) void fill_kernel(const int* __restrict__ src,
                                                   const int* __restrict__ dst,
                                                   const float* __restrict__ w,
                                                   int* __restrict__ cursor,
                                                   int2* __restrict__ csr_ew, int E)
{
    const int i = blockIdx.x * 256 + threadIdx.x;
    if (i < E) {
        const int t   = dst[i];
        const int pos = atomicAdd(&cursor[t], 1);
        int2 ew;
        ew.x = src[i];
        ew.y = __float_as_int(w[i]);
        csr_ew[pos] = ew;
    }
}

// ---------------- pull segment-sum: out[n] = sum_e w_e * h[src_e] ----------------
template<int D>
__global__ __launch_bounds__(256) void pull_kernel(const float* __restrict__ h,
                                                   const int* __restrict__ row_ptr,
                                                   const int2* __restrict__ csr_ew,
                                                   float* __restrict__ out, int n_nodes)
{
    const int wave = threadIdx.x >> 6;
    const int lane = threadIdx.x & 63;
    const int node = blockIdx.x * 4 + wave;
    if (node >= n_nodes) return;

    const int beg = row_ptr[node];
    const int end = row_ptr[node + 1];

    if (D == 128) {
        float2 a0 = make_float2(0.f, 0.f);
        float2 a1 = make_float2(0.f, 0.f);
        int i = beg;
        for (; i + 1 < end; i += 2) {
            const int2 e0 = csr_ew[i];
            const int2 e1 = csr_ew[i + 1];
            const float w0 = __int_as_float(e0.y);
            const float w1 = __int_as_float(e1.y);
            const float2 v0 = *reinterpret_cast<const float2*>(&h[(size_t)e0.x * 128 + 2 * lane]);
            const float2 v1 = *reinterpret_cast<const float2*>(&h[(size_t)e1.x * 128 + 2 * lane]);
            a0.x = fmaf(v0.x, w0, a0.x); a0.y = fmaf(v0.y, w0, a0.y);
            a1.x = fmaf(v1.x, w1, a1.x); a1.y = fmaf(v1.y, w1, a1.y);
        }
        if (i < end) {
            const int2 e0 = csr_ew[i];
            const float w0 = __int_as_float(e0.y);
            const float2 v0 = *reinterpret_cast<const float2*>(&h[(size_t)e0.x * 128 + 2 * lane]);
            a0.x = fmaf(v0.x, w0, a0.x); a0.y = fmaf(v0.y, w0, a0.y);
        }
        a0.x += a1.x; a0.y += a1.y;
        *reinterpret_cast<float2*>(&out[(size_t)node * 128 + 2 * lane]) = a0;
    } else {
        float a0 = 0.f, a1 = 0.f;
        int i = beg;
        for (; i + 1 < end; i += 2) {
            const int2 e0 = csr_ew[i];
            const int2 e1 = csr_ew[i + 1];
            a0 = fmaf(h[(size_t)e0.x * 64 + lane], __int_as_float(e0.y), a0);
            a1 = fmaf(h[(size_t)e1.x * 64 + lane], __int_as_float(e1.y), a1);
        }
        if (i < end) {
            const int2 e0 = csr_ew[i];
            a0 = fmaf(h[(size_t)e0.x * 64 + lane], __int_as_float(e0.y), a0);
        }
        out[(size_t)node * 64 + lane] = a0 + a1;
    }
}

extern "C" void kernel_launch(void* const* d_in, const int* in_sizes, int n_in,
                              void* d_out, int out_size, void* d_ws, size_t ws_size,
                              hipStream_t stream)
{
    const float* x   = (const float*)d_in[0];
    const int*   src = (const int*)  d_in[1];
    const int*   dst = (const int*)  d_in[2];
    const float* w   = (const float*)d_in[3];
    const float* W1  = (const float*)d_in[4];
    const float* b1  = (const float*)d_in[5];
    const float* W2  = (const float*)d_in[6];
    const float* b2  = (const float*)d_in[7];
    const float* W3  = (const float*)d_in[8];
    const float* b3  = (const float*)d_in[9];

    const int E = in_sizes[1];
    const int M = N_NODES;

    // workspace layout (8B-aligned segments)
    float* bufA    = (float*)d_ws;                        // M*128 f32
    float* bufB    = bufA + (size_t)M * 128;              // M*128 f32
    int2*  csr_ew  = (int2*)(bufB + (size_t)M * 128);     // E pairs (8 B)
    int*   row_ptr = (int*)(csr_ew + E);                  // 50048
    int*   cursor  = row_ptr + 50048;                     // 50048
    int*   deg     = cursor + 50048;                      // 50048
    int*   partial = deg + 50048;                         // 256

    const int eb = (E + 255) / 256;           // edge blocks
    const int nb = (M + 255) / 256;           // node blocks (196)
    const int gemm_blocks = (M + 63) / 64;    // 782
    const int pull_blocks = (M + 3) / 4;

    // ---- CSR build (once per call, reused by all 3 layers) ----
    hipMemsetAsync(deg, 0, (size_t)M * sizeof(int), stream);
    hist_kernel<<<eb, 256, 0, stream>>>(dst, deg, E);
    scan_partial<<<nb, 256, 0, stream>>>(deg, partial, M);
    scan_offsets<<<1, 256, 0, stream>>>(partial, nb);
    scan_final<<<nb, 256, 0, stream>>>(deg, partial, row_ptr, cursor, M, E);
    fill_kernel<<<eb, 256, 0, stream>>>(src, dst, w, cursor, csr_ew, E);

    // ---- Layer 1 ----
    gemm_kernel<256, 128, false><<<gemm_blocks, 256, 0, stream>>>(x, W1, b1, bufA, M);
    pull_kernel<128><<<pull_blocks, 256, 0, stream>>>(bufA, row_ptr, csr_ew, bufB, M);

    // ---- Layer 2 ----
    gemm_kernel<128, 128, true><<<gemm_blocks, 256, 0, stream>>>(bufB, W2, b2, bufA, M);
    pull_kernel<128><<<pull_blocks, 256, 0, stream>>>(bufA, row_ptr, csr_ew, bufB, M);

    // ---- Layer 3 ----
    gemm_kernel<128, 64, true><<<gemm_blocks, 256, 0, stream>>>(bufB, W3, b3, bufA, M);
    pull_kernel<64><<<pull_blocks, 256, 0, stream>>>(bufA, row_ptr, csr_ew, (float*)d_out, M);
}

// Round 5
// 329.840 us; speedup vs baseline: 10.6397x; 1.1380x over previous
//
#include <hip/hip_runtime.h>
#include <hip/hip_bf16.h>

#define N_NODES 50000

using short8  = __attribute__((ext_vector_type(8))) short;
using floatx4 = __attribute__((ext_vector_type(4))) float;

__device__ inline short f32_to_bf16_bits(float f) {
    __hip_bfloat16 h = __float2bfloat16(f);
    return *reinterpret_cast<short*>(&h);
}

// ---------------- MFMA GEMM: C_bf16[M,N] = A[M,K] @ W[K,N] + b ----------------
// WT is W transposed [N,K] bf16. All B-fragments register-resident (W is tiny).
// 4 waves/block, wave owns N/4 cols; block does 4 stripes of 16 rows.
template<int K, int N, bool A_F32>
__global__ __launch_bounds__(256) void mfma_gemm(const void* __restrict__ Araw,
                                                 const short* __restrict__ WT,
                                                 const float* __restrict__ bias,
                                                 short* __restrict__ C, int M)
{
    constexpr int CW  = N / 4;     // cols per wave (32 or 16)
    constexpr int TPW = CW / 16;   // 16x16 tiles per wave (2 or 1)
    constexpr int KS  = K / 32;    // K steps

    const int tid  = threadIdx.x;
    const int wave = tid >> 6;
    const int lane = tid & 63;
    const int l15  = lane & 15;
    const int lk   = (lane >> 4) * 8;
    const int n0   = wave * CW;

    // B prologue: fragment (lane l) covers WT[n0+t*16+(l&15)][ks*32+(l>>4)*8 .. +7]
    short8 bfrag[TPW][KS];
#pragma unroll
    for (int t = 0; t < TPW; ++t)
#pragma unroll
        for (int ks = 0; ks < KS; ++ks)
            bfrag[t][ks] = *reinterpret_cast<const short8*>(
                &WT[(size_t)(n0 + t * 16 + l15) * K + ks * 32 + lk]);

    float bv[TPW];
#pragma unroll
    for (int t = 0; t < TPW; ++t) bv[t] = bias[n0 + t * 16 + l15];

    const float* Af = (const float*)Araw;
    const short* Ab = (const short*)Araw;

    const int rbase = blockIdx.x * 64;
#pragma unroll
    for (int s = 0; s < 4; ++s) {
        const int r0 = rbase + s * 16;
        if (r0 >= M) break;

        floatx4 acc[TPW];
#pragma unroll
        for (int t = 0; t < TPW; ++t) acc[t] = (floatx4){0.f, 0.f, 0.f, 0.f};

        const int arow = min(r0 + l15, M - 1);   // clamp: masked rows never stored
#pragma unroll
        for (int ks = 0; ks < KS; ++ks) {
            short8 af;
            if (A_F32) {
                const float4 v0 = *reinterpret_cast<const float4*>(&Af[(size_t)arow * K + ks * 32 + lk]);
                const float4 v1 = *reinterpret_cast<const float4*>(&Af[(size_t)arow * K + ks * 32 + lk + 4]);
                af[0] = f32_to_bf16_bits(v0.x); af[1] = f32_to_bf16_bits(v0.y);
                af[2] = f32_to_bf16_bits(v0.z); af[3] = f32_to_bf16_bits(v0.w);
                af[4] = f32_to_bf16_bits(v1.x); af[5] = f32_to_bf16_bits(v1.y);
                af[6] = f32_to_bf16_bits(v1.z); af[7] = f32_to_bf16_bits(v1.w);
            } else {
                af = *reinterpret_cast<const short8*>(&Ab[(size_t)arow * K + ks * 32 + lk]);
            }
#pragma unroll
            for (int t = 0; t < TPW; ++t)
                acc[t] = __builtin_amdgcn_mfma_f32_16x16x32_bf16(af, bfrag[t][ks], acc[t], 0, 0, 0);
        }

        // C/D layout: col = lane&15, row = (lane>>4)*4 + reg   [HW-verified]
        const int rowg = (lane >> 4) * 4;
#pragma unroll
        for (int t = 0; t < TPW; ++t)
#pragma unroll
            for (int j = 0; j < 4; ++j) {
                const int gr = r0 + rowg + j;
                if (gr < M)
                    C[(size_t)gr * N + n0 + t * 16 + l15] = f32_to_bf16_bits(acc[t][j] + bv[t]);
            }
    }
}

// ---------------- W -> W^T bf16 ----------------
__global__ __launch_bounds__(256) void wt_kernel(const float* __restrict__ W,
                                                 short* __restrict__ WT, int K, int N)
{
    const int i = blockIdx.x * 256 + threadIdx.x;
    if (i < K * N) {
        const int k = i / N, n = i % N;
        WT[(size_t)n * K + k] = f32_to_bf16_bits(W[i]);
    }
}

// ---------------- CSR build ----------------
__global__ __launch_bounds__(256) void hist_kernel(const int* __restrict__ dst,
                                                   int* __restrict__ deg, int E)
{
    const int i = blockIdx.x * 256 + threadIdx.x;
    if (i < E) atomicAdd(&deg[dst[i]], 1);
}

__global__ __launch_bounds__(256) void scan_partial(const int* __restrict__ deg,
                                                    int* __restrict__ partial, int n)
{
    __shared__ int red[4];
    const int t = threadIdx.x;
    const int i = blockIdx.x * 256 + t;
    int v = (i < n) ? deg[i] : 0;
#pragma unroll
    for (int off = 32; off > 0; off >>= 1) v += __shfl_down(v, off, 64);
    if ((t & 63) == 0) red[t >> 6] = v;
    __syncthreads();
    if (t == 0) partial[blockIdx.x] = red[0] + red[1] + red[2] + red[3];
}

__global__ __launch_bounds__(256) void scan_offsets(int* __restrict__ partial, int nb)
{
    __shared__ int s[256];
    const int t = threadIdx.x;
    const int v = (t < nb) ? partial[t] : 0;
    s[t] = v;
    __syncthreads();
#pragma unroll
    for (int off = 1; off < 256; off <<= 1) {
        const int tmp = (t >= off) ? s[t - off] : 0;
        __syncthreads();
        s[t] += tmp;
        __syncthreads();
    }
    if (t < nb) partial[t] = s[t] - v;
}

__global__ __launch_bounds__(256) void scan_final(const int* __restrict__ deg,
                                                  const int* __restrict__ partial,
                                                  int* __restrict__ row_ptr,
                                                  int* __restrict__ cursor, int n, int E)
{
    __shared__ int s[256];
    const int t = threadIdx.x;
    const int i = blockIdx.x * 256 + t;
    const int v = (i < n) ? deg[i] : 0;
    s[t] = v;
    __syncthreads();
#pragma unroll
    for (int off = 1; off < 256; off <<= 1) {
        const int tmp = (t >= off) ? s[t - off] : 0;
        __syncthreads();
        s[t] += tmp;
        __syncthreads();
    }
    const int excl = s[t] - v + partial[blockIdx.x];
    if (i < n) { row_ptr[i] = excl; cursor[i] = excl; }
    if (i == 0) row_ptr[n] = E;
}

__global__ __launch_bounds__(256) void fill_kernel(const int* __restrict__ src,
                                                   const int* __restrict__ dst,
                                                   const float* __restrict__ w,
                                                   int* __restrict__ cursor,
                                                   int2* __restrict__ csr_ew, int E)
{
    const int i = blockIdx.x * 256 + threadIdx.x;
    if (i < E) {
        const int t   = dst[i];
        const int pos = atomicAdd(&cursor[t], 1);
        int2 ew;
        ew.x = src[i];
        ew.y = __float_as_int(w[i]);
        csr_ew[pos] = ew;
    }
}

// ---------------- pull (bf16 h): out[n] = sum_e w_e * h[src_e] ----------------
// D=128: lane owns 2 dims packed in one u32.
template<bool RELU>
__global__ __launch_bounds__(256) void pull128_bf(const unsigned int* __restrict__ h,
                                                  const int* __restrict__ row_ptr,
                                                  const int2* __restrict__ csr_ew,
                                                  unsigned int* __restrict__ out, int n_nodes)
{
    const int wave = threadIdx.x >> 6;
    const int lane = threadIdx.x & 63;
    const int node = blockIdx.x * 4 + wave;
    if (node >= n_nodes) return;

    const int beg = row_ptr[node];
    const int end = row_ptr[node + 1];

    float a0x = 0.f, a0y = 0.f, a1x = 0.f, a1y = 0.f;
    int i = beg;
    for (; i + 1 < end; i += 2) {
        const int2 e0 = csr_ew[i];
        const int2 e1 = csr_ew[i + 1];
        const float w0 = __int_as_float(e0.y);
        const float w1 = __int_as_float(e1.y);
        const unsigned int p0 = h[(size_t)e0.x * 64 + lane];
        const unsigned int p1 = h[(size_t)e1.x * 64 + lane];
        a0x = fmaf(__int_as_float(p0 << 16), w0, a0x);
        a0y = fmaf(__int_as_float(p0 & 0xffff0000u), w0, a0y);
        a1x = fmaf(__int_as_float(p1 << 16), w1, a1x);
        a1y = fmaf(__int_as_float(p1 & 0xffff0000u), w1, a1y);
    }
    if (i < end) {
        const int2 e0 = csr_ew[i];
        const float w0 = __int_as_float(e0.y);
        const unsigned int p0 = h[(size_t)e0.x * 64 + lane];
        a0x = fmaf(__int_as_float(p0 << 16), w0, a0x);
        a0y = fmaf(__int_as_float(p0 & 0xffff0000u), w0, a0y);
    }
    float ax = a0x + a1x, ay = a0y + a1y;
    if (RELU) { ax = fmaxf(ax, 0.f); ay = fmaxf(ay, 0.f); }
    const unsigned int lo = (unsigned short)f32_to_bf16_bits(ax);
    const unsigned int hi = (unsigned short)f32_to_bf16_bits(ay);
    out[(size_t)node * 64 + lane] = lo | (hi << 16);
}

// D=64: lane owns 1 dim; f32 output (final layer, no relu).
__global__ __launch_bounds__(256) void pull64_bf(const unsigned short* __restrict__ h,
                                                 const int* __restrict__ row_ptr,
                                                 const int2* __restrict__ csr_ew,
                                                 float* __restrict__ out, int n_nodes)
{
    const int wave = threadIdx.x >> 6;
    const int lane = threadIdx.x & 63;
    const int node = blockIdx.x * 4 + wave;
    if (node >= n_nodes) return;

    const int beg = row_ptr[node];
    const int end = row_ptr[node + 1];

    float a0 = 0.f, a1 = 0.f;
    int i = beg;
    for (; i + 1 < end; i += 2) {
        const int2 e0 = csr_ew[i];
        const int2 e1 = csr_ew[i + 1];
        const unsigned int v0 = h[(size_t)e0.x * 64 + lane];
        const unsigned int v1 = h[(size_t)e1.x * 64 + lane];
        a0 = fmaf(__int_as_float(v0 << 16), __int_as_float(e0.y), a0);
        a1 = fmaf(__int_as_float(v1 << 16), __int_as_float(e1.y), a1);
    }
    if (i < end) {
        const int2 e0 = csr_ew[i];
        const unsigned int v0 = h[(size_t)e0.x * 64 + lane];
        a0 = fmaf(__int_as_float(v0 << 16), __int_as_float(e0.y), a0);
    }
    out[(size_t)node * 64 + lane] = a0 + a1;
}

extern "C" void kernel_launch(void* const* d_in, const int* in_sizes, int n_in,
                              void* d_out, int out_size, void* d_ws, size_t ws_size,
                              hipStream_t stream)
{
    const float* x   = (const float*)d_in[0];
    const int*   src = (const int*)  d_in[1];
    const int*   dst = (const int*)  d_in[2];
    const float* w   = (const float*)d_in[3];
    const float* W1  = (const float*)d_in[4];
    const float* b1  = (const float*)d_in[5];
    const float* W2  = (const float*)d_in[6];
    const float* b2  = (const float*)d_in[7];
    const float* W3  = (const float*)d_in[8];
    const float* b3  = (const float*)d_in[9];

    const int E = in_sizes[1];
    const int M = N_NODES;

    // workspace layout
    short* hA  = (short*)d_ws;                    // M*128 bf16 (h1 / h3)
    short* hB  = hA + (size_t)M * 128;            // M*128 bf16 (a1 / a2)
    short* WT1 = hB + (size_t)M * 128;            // 128*256
    short* WT2 = WT1 + 128 * 256;                 // 128*128
    short* WT3 = WT2 + 128 * 128;                 // 64*128
    int2*  csr_ew  = (int2*)(WT3 + 64 * 128);     // E pairs (8 B); offset stays 16B-aligned
    int*   row_ptr = (int*)(csr_ew + E);          // 50048
    int*   cursor  = row_ptr + 50048;             // 50048
    int*   deg     = cursor + 50048;              // 50048
    int*   partial = deg + 50048;                 // 256

    const int eb = (E + 255) / 256;
    const int nb = (M + 255) / 256;
    const int gemm_blocks = (M + 63) / 64;        // 782
    const int pull_blocks = (M + 3) / 4;          // 12500

    // ---- weight transposes (bf16) ----
    wt_kernel<<<(256 * 128 + 255) / 256, 256, 0, stream>>>(W1, WT1, 256, 128);
    wt_kernel<<<(128 * 128 + 255) / 256, 256, 0, stream>>>(W2, WT2, 128, 128);
    wt_kernel<<<(128 * 64 + 255) / 256, 256, 0, stream>>>(W3, WT3, 128, 64);

    // ---- CSR build ----
    hipMemsetAsync(deg, 0, (size_t)M * sizeof(int), stream);
    hist_kernel<<<eb, 256, 0, stream>>>(dst, deg, E);
    scan_partial<<<nb, 256, 0, stream>>>(deg, partial, M);
    scan_offsets<<<1, 256, 0, stream>>>(partial, nb);
    scan_final<<<nb, 256, 0, stream>>>(deg, partial, row_ptr, cursor, M, E);
    fill_kernel<<<eb, 256, 0, stream>>>(src, dst, w, cursor, csr_ew, E);

    // ---- Layer 1 ----
    mfma_gemm<256, 128, true><<<gemm_blocks, 256, 0, stream>>>(x, WT1, b1, hA, M);
    pull128_bf<true><<<pull_blocks, 256, 0, stream>>>((const unsigned int*)hA, row_ptr, csr_ew,
                                                      (unsigned int*)hB, M);
    // ---- Layer 2 ----
    mfma_gemm<128, 128, false><<<gemm_blocks, 256, 0, stream>>>(hB, WT2, b2, hA, M);
    pull128_bf<true><<<pull_blocks, 256, 0, stream>>>((const unsigned int*)hA, row_ptr, csr_ew,
                                                      (unsigned int*)hB, M);
    // ---- Layer 3 ----
    mfma_gemm<128, 64, false><<<gemm_blocks, 256, 0, stream>>>(hB, WT3, b3, hA, M);
    pull64_bf<<<pull_blocks, 256, 0, stream>>>((const unsigned short*)hA, row_ptr, csr_ew,
                                               (float*)d_out, M);
}

// Round 6
// 251.514 us; speedup vs baseline: 13.9531x; 1.3114x over previous
//
#include <hip/hip_runtime.h>
#include <hip/hip_bf16.h>

#define N_NODES 50000

using short8  = __attribute__((ext_vector_type(8))) short;
using floatx4 = __attribute__((ext_vector_type(4))) float;

__device__ inline short f32_to_bf16_bits(float f) {
    __hip_bfloat16 h = __float2bfloat16(f);
    return *reinterpret_cast<short*>(&h);
}

// ---------------- MFMA GEMM: C_bf16[M,N] = A[M,K] @ W[K,N] + b ----------------
template<int K, int N, bool A_F32>
__global__ __launch_bounds__(256) void mfma_gemm(const void* __restrict__ Araw,
                                                 const short* __restrict__ WT,
                                                 const float* __restrict__ bias,
                                                 short* __restrict__ C, int M)
{
    constexpr int CW  = N / 4;
    constexpr int TPW = CW / 16;
    constexpr int KS  = K / 32;

    const int tid  = threadIdx.x;
    const int wave = tid >> 6;
    const int lane = tid & 63;
    const int l15  = lane & 15;
    const int lk   = (lane >> 4) * 8;
    const int n0   = wave * CW;

    short8 bfrag[TPW][KS];
#pragma unroll
    for (int t = 0; t < TPW; ++t)
#pragma unroll
        for (int ks = 0; ks < KS; ++ks)
            bfrag[t][ks] = *reinterpret_cast<const short8*>(
                &WT[(size_t)(n0 + t * 16 + l15) * K + ks * 32 + lk]);

    float bv[TPW];
#pragma unroll
    for (int t = 0; t < TPW; ++t) bv[t] = bias[n0 + t * 16 + l15];

    const float* Af = (const float*)Araw;
    const short* Ab = (const short*)Araw;

    const int rbase = blockIdx.x * 64;
#pragma unroll
    for (int s = 0; s < 4; ++s) {
        const int r0 = rbase + s * 16;
        if (r0 >= M) break;

        floatx4 acc[TPW];
#pragma unroll
        for (int t = 0; t < TPW; ++t) acc[t] = (floatx4){0.f, 0.f, 0.f, 0.f};

        const int arow = min(r0 + l15, M - 1);
#pragma unroll
        for (int ks = 0; ks < KS; ++ks) {
            short8 af;
            if (A_F32) {
                const float4 v0 = *reinterpret_cast<const float4*>(&Af[(size_t)arow * K + ks * 32 + lk]);
                const float4 v1 = *reinterpret_cast<const float4*>(&Af[(size_t)arow * K + ks * 32 + lk + 4]);
                af[0] = f32_to_bf16_bits(v0.x); af[1] = f32_to_bf16_bits(v0.y);
                af[2] = f32_to_bf16_bits(v0.z); af[3] = f32_to_bf16_bits(v0.w);
                af[4] = f32_to_bf16_bits(v1.x); af[5] = f32_to_bf16_bits(v1.y);
                af[6] = f32_to_bf16_bits(v1.z); af[7] = f32_to_bf16_bits(v1.w);
            } else {
                af = *reinterpret_cast<const short8*>(&Ab[(size_t)arow * K + ks * 32 + lk]);
            }
#pragma unroll
            for (int t = 0; t < TPW; ++t)
                acc[t] = __builtin_amdgcn_mfma_f32_16x16x32_bf16(af, bfrag[t][ks], acc[t], 0, 0, 0);
        }

        const int rowg = (lane >> 4) * 4;
#pragma unroll
        for (int t = 0; t < TPW; ++t)
#pragma unroll
            for (int j = 0; j < 4; ++j) {
                const int gr = r0 + rowg + j;
                if (gr < M)
                    C[(size_t)gr * N + n0 + t * 16 + l15] = f32_to_bf16_bits(acc[t][j] + bv[t]);
            }
    }
}

// ---------------- all three W -> W^T bf16 in one kernel ----------------
__global__ __launch_bounds__(256) void wt_all(const float* __restrict__ W1, short* __restrict__ WT1,
                                              const float* __restrict__ W2, short* __restrict__ WT2,
                                              const float* __restrict__ W3, short* __restrict__ WT3)
{
    const int i = blockIdx.x * 256 + threadIdx.x;
    if (i < 256 * 128) {
        const int k = i >> 7, n = i & 127;
        WT1[(size_t)n * 256 + k] = f32_to_bf16_bits(W1[i]);
    }
    if (i < 128 * 128) {
        const int k = i >> 7, n = i & 127;
        WT2[(size_t)n * 128 + k] = f32_to_bf16_bits(W2[i]);
    }
    if (i < 128 * 64) {
        const int k = i >> 6, n = i & 63;
        WT3[(size_t)n * 128 + k] = f32_to_bf16_bits(W3[i]);
    }
}

// ---------------- CSR build ----------------
__global__ __launch_bounds__(256) void hist_kernel(const int* __restrict__ dst,
                                                   int* __restrict__ deg, int E)
{
    const int i = blockIdx.x * 256 + threadIdx.x;
    if (i < E) atomicAdd(&deg[dst[i]], 1);
}

__global__ __launch_bounds__(256) void scan_partial(const int* __restrict__ deg,
                                                    int* __restrict__ partial, int n)
{
    __shared__ int red[4];
    const int t = threadIdx.x;
    const int i = blockIdx.x * 256 + t;
    int v = (i < n) ? deg[i] : 0;
#pragma unroll
    for (int off = 32; off > 0; off >>= 1) v += __shfl_down(v, off, 64);
    if ((t & 63) == 0) red[t >> 6] = v;
    __syncthreads();
    if (t == 0) partial[blockIdx.x] = red[0] + red[1] + red[2] + red[3];
}

__global__ __launch_bounds__(256) void scan_offsets(int* __restrict__ partial, int nb)
{
    __shared__ int s[256];
    const int t = threadIdx.x;
    const int v = (t < nb) ? partial[t] : 0;
    s[t] = v;
    __syncthreads();
#pragma unroll
    for (int off = 1; off < 256; off <<= 1) {
        const int tmp = (t >= off) ? s[t - off] : 0;
        __syncthreads();
        s[t] += tmp;
        __syncthreads();
    }
    if (t < nb) partial[t] = s[t] - v;
}

__global__ __launch_bounds__(256) void scan_final(const int* __restrict__ deg,
                                                  const int* __restrict__ partial,
                                                  int* __restrict__ row_ptr,
                                                  int* __restrict__ cursor, int n, int E)
{
    __shared__ int s[256];
    const int t = threadIdx.x;
    const int i = blockIdx.x * 256 + t;
    const int v = (i < n) ? deg[i] : 0;
    s[t] = v;
    __syncthreads();
#pragma unroll
    for (int off = 1; off < 256; off <<= 1) {
        const int tmp = (t >= off) ? s[t - off] : 0;
        __syncthreads();
        s[t] += tmp;
        __syncthreads();
    }
    const int excl = s[t] - v + partial[blockIdx.x];
    if (i < n) { row_ptr[i] = excl; cursor[i] = excl; }
    if (i == 0) row_ptr[n] = E;
}

__global__ __launch_bounds__(256) void fill_kernel(const int* __restrict__ src,
                                                   const int* __restrict__ dst,
                                                   const float* __restrict__ w,
                                                   int* __restrict__ cursor,
                                                   int2* __restrict__ csr_ew, int E)
{
    const int i = blockIdx.x * 256 + threadIdx.x;
    if (i < E) {
        const int t   = dst[i];
        const int pos = atomicAdd(&cursor[t], 1);
        int2 ew;
        ew.x = src[i];
        ew.y = __float_as_int(w[i]);
        csr_ew[pos] = ew;
    }
}

// ---------------- pull (bf16 h, D=128): one wave per node ----------------
// Coalesced edge prefetch (lane-owned), shfl broadcast, 4-deep gather ILP.
template<bool RELU>
__global__ __launch_bounds__(256) void pull128_bf(const unsigned int* __restrict__ h,
                                                  const int* __restrict__ row_ptr,
                                                  const int2* __restrict__ csr_ew,
                                                  unsigned int* __restrict__ out, int n_nodes)
{
    const int wave = threadIdx.x >> 6;
    const int lane = threadIdx.x & 63;
    const int node = blockIdx.x * 4 + wave;
    if (node >= n_nodes) return;

    const int beg = row_ptr[node];
    const int end = row_ptr[node + 1];

    float ax0 = 0.f, ay0 = 0.f, ax1 = 0.f, ay1 = 0.f;
    float ax2 = 0.f, ay2 = 0.f, ax3 = 0.f, ay3 = 0.f;

    for (int c = beg; c < end; c += 64) {
        const int idx = c + lane;
        int2 ew = make_int2(0, 0);
        if (idx < end) ew = csr_ew[idx];
        const int cnt = min(64, end - c);

        int j = 0;
        for (; j + 4 <= cnt; j += 4) {
            const int   s0 = __shfl(ew.x, j);
            const int   s1 = __shfl(ew.x, j + 1);
            const int   s2 = __shfl(ew.x, j + 2);
            const int   s3 = __shfl(ew.x, j + 3);
            const float w0 = __int_as_float(__shfl(ew.y, j));
            const float w1 = __int_as_float(__shfl(ew.y, j + 1));
            const float w2 = __int_as_float(__shfl(ew.y, j + 2));
            const float w3 = __int_as_float(__shfl(ew.y, j + 3));
            const unsigned int p0 = h[(size_t)s0 * 64 + lane];
            const unsigned int p1 = h[(size_t)s1 * 64 + lane];
            const unsigned int p2 = h[(size_t)s2 * 64 + lane];
            const unsigned int p3 = h[(size_t)s3 * 64 + lane];
            ax0 = fmaf(__int_as_float(p0 << 16), w0, ax0);
            ay0 = fmaf(__int_as_float(p0 & 0xffff0000u), w0, ay0);
            ax1 = fmaf(__int_as_float(p1 << 16), w1, ax1);
            ay1 = fmaf(__int_as_float(p1 & 0xffff0000u), w1, ay1);
            ax2 = fmaf(__int_as_float(p2 << 16), w2, ax2);
            ay2 = fmaf(__int_as_float(p2 & 0xffff0000u), w2, ay2);
            ax3 = fmaf(__int_as_float(p3 << 16), w3, ax3);
            ay3 = fmaf(__int_as_float(p3 & 0xffff0000u), w3, ay3);
        }
        for (; j < cnt; ++j) {
            const int   s0 = __shfl(ew.x, j);
            const float w0 = __int_as_float(__shfl(ew.y, j));
            const unsigned int p0 = h[(size_t)s0 * 64 + lane];
            ax0 = fmaf(__int_as_float(p0 << 16), w0, ax0);
            ay0 = fmaf(__int_as_float(p0 & 0xffff0000u), w0, ay0);
        }
    }

    float ax = (ax0 + ax1) + (ax2 + ax3);
    float ay = (ay0 + ay1) + (ay2 + ay3);
    if (RELU) { ax = fmaxf(ax, 0.f); ay = fmaxf(ay, 0.f); }
    const unsigned int lo = (unsigned short)f32_to_bf16_bits(ax);
    const unsigned int hi = (unsigned short)f32_to_bf16_bits(ay);
    out[(size_t)node * 64 + lane] = lo | (hi << 16);
}

// ---------------- pull (bf16 h, D=64): two nodes per wave, f32 out ----------------
__global__ __launch_bounds__(256) void pull64_bf(const unsigned int* __restrict__ h,
                                                 const int* __restrict__ row_ptr,
                                                 const int2* __restrict__ csr_ew,
                                                 float2* __restrict__ out, int n_nodes)
{
    const int wave = threadIdx.x >> 6;
    const int lane = threadIdx.x & 63;
    const int half = lane >> 5;          // which node within the wave
    const int l32  = lane & 31;
    const int node = blockIdx.x * 8 + wave * 2 + half;
    if (node >= n_nodes) return;

    const int beg = row_ptr[node];
    const int end = row_ptr[node + 1];

    float ax0 = 0.f, ay0 = 0.f, ax1 = 0.f, ay1 = 0.f;
    float ax2 = 0.f, ay2 = 0.f, ax3 = 0.f, ay3 = 0.f;

    for (int c = beg; c < end; c += 32) {
        const int idx = c + l32;
        int2 ew = make_int2(0, 0);
        if (idx < end) ew = csr_ew[idx];
        const int cnt = min(32, end - c);

        int j = 0;
        for (; j + 4 <= cnt; j += 4) {
            const int   s0 = __shfl(ew.x, j, 32);
            const int   s1 = __shfl(ew.x, j + 1, 32);
            const int   s2 = __shfl(ew.x, j + 2, 32);
            const int   s3 = __shfl(ew.x, j + 3, 32);
            const float w0 = __int_as_float(__shfl(ew.y, j, 32));
            const float w1 = __int_as_float(__shfl(ew.y, j + 1, 32));
            const float w2 = __int_as_float(__shfl(ew.y, j + 2, 32));
            const float w3 = __int_as_float(__shfl(ew.y, j + 3, 32));
            const unsigned int p0 = h[(size_t)s0 * 32 + l32];
            const unsigned int p1 = h[(size_t)s1 * 32 + l32];
            const unsigned int p2 = h[(size_t)s2 * 32 + l32];
            const unsigned int p3 = h[(size_t)s3 * 32 + l32];
            ax0 = fmaf(__int_as_float(p0 << 16), w0, ax0);
            ay0 = fmaf(__int_as_float(p0 & 0xffff0000u), w0, ay0);
            ax1 = fmaf(__int_as_float(p1 << 16), w1, ax1);
            ay1 = fmaf(__int_as_float(p1 & 0xffff0000u), w1, ay1);
            ax2 = fmaf(__int_as_float(p2 << 16), w2, ax2);
            ay2 = fmaf(__int_as_float(p2 & 0xffff0000u), w2, ay2);
            ax3 = fmaf(__int_as_float(p3 << 16), w3, ax3);
            ay3 = fmaf(__int_as_float(p3 & 0xffff0000u), w3, ay3);
        }
        for (; j < cnt; ++j) {
            const int   s0 = __shfl(ew.x, j, 32);
            const float w0 = __int_as_float(__shfl(ew.y, j, 32));
            const unsigned int p0 = h[(size_t)s0 * 32 + l32];
            ax0 = fmaf(__int_as_float(p0 << 16), w0, ax0);
            ay0 = fmaf(__int_as_float(p0 & 0xffff0000u), w0, ay0);
        }
    }

    const float ax = (ax0 + ax1) + (ax2 + ax3);
    const float ay = (ay0 + ay1) + (ay2 + ay3);
    out[(size_t)node * 32 + l32] = make_float2(ax, ay);
}

extern "C" void kernel_launch(void* const* d_in, const int* in_sizes, int n_in,
                              void* d_out, int out_size, void* d_ws, size_t ws_size,
                              hipStream_t stream)
{
    const float* x   = (const float*)d_in[0];
    const int*   src = (const int*)  d_in[1];
    const int*   dst = (const int*)  d_in[2];
    const float* w   = (const float*)d_in[3];
    const float* W1  = (const float*)d_in[4];
    const float* b1  = (const float*)d_in[5];
    const float* W2  = (const float*)d_in[6];
    const float* b2  = (const float*)d_in[7];
    const float* W3  = (const float*)d_in[8];
    const float* b3  = (const float*)d_in[9];

    const int E = in_sizes[1];
    const int M = N_NODES;

    // workspace layout
    short* hA  = (short*)d_ws;                    // M*128 bf16
    short* hB  = hA + (size_t)M * 128;            // M*128 bf16
    short* WT1 = hB + (size_t)M * 128;            // 128*256
    short* WT2 = WT1 + 128 * 256;                 // 128*128
    short* WT3 = WT2 + 128 * 128;                 // 64*128
    int2*  csr_ew  = (int2*)(WT3 + 64 * 128);     // E pairs
    int*   row_ptr = (int*)(csr_ew + E);          // 50048
    int*   cursor  = row_ptr + 50048;             // 50048
    int*   deg     = cursor + 50048;              // 50048
    int*   partial = deg + 50048;                 // 256

    const int eb = (E + 255) / 256;
    const int nb = (M + 255) / 256;
    const int gemm_blocks = (M + 63) / 64;

    // ---- weights + CSR build ----
    wt_all<<<(256 * 128 + 255) / 256, 256, 0, stream>>>(W1, WT1, W2, WT2, W3, WT3);
    hipMemsetAsync(deg, 0, (size_t)M * sizeof(int), stream);
    hist_kernel<<<eb, 256, 0, stream>>>(dst, deg, E);
    scan_partial<<<nb, 256, 0, stream>>>(deg, partial, M);
    scan_offsets<<<1, 256, 0, stream>>>(partial, nb);
    scan_final<<<nb, 256, 0, stream>>>(deg, partial, row_ptr, cursor, M, E);
    fill_kernel<<<eb, 256, 0, stream>>>(src, dst, w, cursor, csr_ew, E);

    // ---- Layer 1 ----
    mfma_gemm<256, 128, true><<<gemm_blocks, 256, 0, stream>>>(x, WT1, b1, hA, M);
    pull128_bf<true><<<(M + 3) / 4, 256, 0, stream>>>((const unsigned int*)hA, row_ptr, csr_ew,
                                                      (unsigned int*)hB, M);
    // ---- Layer 2 ----
    mfma_gemm<128, 128, false><<<gemm_blocks, 256, 0, stream>>>(hB, WT2, b2, hA, M);
    pull128_bf<true><<<(M + 3) / 4, 256, 0, stream>>>((const unsigned int*)hA, row_ptr, csr_ew,
                                                      (unsigned int*)hB, M);
    // ---- Layer 3 ----
    mfma_gemm<128, 64, false><<<gemm_blocks, 256, 0, stream>>>(hB, WT3, b3, hA, M);
    pull64_bf<<<(M + 7) / 8, 256, 0, stream>>>((const unsigned int*)hA, row_ptr, csr_ew,
                                               (float2*)d_out, M);
}